// Round 10
// baseline (758.742 us; speedup 1.0000x reference)
//
#include <hip/hip_runtime.h>
#include <math.h>

#define N_T 80000
#define N_S 160000
#define D_STATE 400
#define D_EMB 350
#define D_DIST 20
#define HDIM 150
#define GI_DIM 1170
#define KP16 1216   // padded K for bf16 shadow / weights

typedef __attribute__((ext_vector_type(8))) short s16x8;
typedef __attribute__((ext_vector_type(4))) float f32x4;
typedef __attribute__((ext_vector_type(2))) float f32x2;

__device__ __forceinline__ unsigned short f2bf(float f) {
    union { float f; unsigned int u; } c; c.f = f;
    unsigned int u = c.u;
    unsigned int r = (u + 0x7fffu + ((u >> 16) & 1u)) >> 16;  // RNE
    return (unsigned short)r;
}
__device__ __forceinline__ float bf2f(unsigned short h) {
    union { unsigned int u; float f; } c; c.u = ((unsigned int)h) << 16;
    return c.f;
}

// ---------------------------------------------------------------------------
// Weight conversion: f32 [K][150] -> bf16 transposed+padded [160][KP]
// ---------------------------------------------------------------------------
__global__ __launch_bounds__(256) void convert_kernel(
    const float* __restrict__ sW1, const float* __restrict__ sW2, const float* __restrict__ sW3,
    const float* __restrict__ aW1, const float* __restrict__ aW2, const float* __restrict__ aW3,
    unsigned short* __restrict__ w1t_m, unsigned short* __restrict__ w2t_m, unsigned short* __restrict__ w3_m,
    unsigned short* __restrict__ w1t_a, unsigned short* __restrict__ w2t_a, unsigned short* __restrict__ w3_a)
{
    int gid = blockIdx.x * 256 + threadIdx.x;
    const int S1 = 160 * 1216, S2 = 160 * 160, S3 = 160, S4 = 160 * 448, S5 = 160 * 160, S6 = 160;
    if (gid < S1) {
        int n = gid / 1216, k = gid % 1216;
        float v = (k < GI_DIM && n < HDIM) ? sW1[k * HDIM + n] : 0.f;
        w1t_m[gid] = f2bf(v); return;
    } gid -= S1;
    if (gid < S2) {
        int n = gid / 160, k = gid % 160;
        float v = (k < HDIM && n < HDIM) ? sW2[k * HDIM + n] : 0.f;
        w2t_m[gid] = f2bf(v); return;
    } gid -= S2;
    if (gid < S3) { w3_m[gid] = (gid < HDIM) ? f2bf(sW3[gid]) : (unsigned short)0; return; } gid -= S3;
    if (gid < S4) {
        int n = gid / 448, k = gid % 448;
        float v = (k < D_STATE && n < HDIM) ? aW1[k * HDIM + n] : 0.f;
        w1t_a[gid] = f2bf(v); return;
    } gid -= S4;
    if (gid < S5) {
        int n = gid / 160, k = gid % 160;
        float v = (k < HDIM && n < HDIM) ? aW2[k * HDIM + n] : 0.f;
        w2t_a[gid] = f2bf(v); return;
    } gid -= S5;
    if (gid < S6) { w3_a[gid] = (gid < HDIM) ? f2bf(aW3[gid]) : (unsigned short)0; }
}

// ---------------------------------------------------------------------------
// g_i build (round-7 proven): one wave per span, batched float4-window
// gathers; batched stores: cached bf16 shadow + nontemporal f32 gi.
// ---------------------------------------------------------------------------
template <int W16>
__global__ __launch_bounds__(256) void gi_build(
    const float* __restrict__ states, const float* __restrict__ embeds,
    const int* __restrict__ starts, const int* __restrict__ widths,
    const float* __restrict__ alfa, const float* __restrict__ wtab,
    float* __restrict__ gi, unsigned short* __restrict__ gi16)
{
    const int wave = threadIdx.x >> 6;
    const int lane = threadIdx.x & 63;
    const int s = blockIdx.x * 4 + wave;

    const int i1 = starts[s];
    const int wdt = widths[s];
    int i2 = i1 + wdt; if (i2 > N_T - 1) i2 = N_T - 1;
    int ie = i1 + 1;  if (ie > N_T - 1) ie = N_T - 1;

    const float e0 = expf(alfa[i1]);
    const float e1 = (wdt > 0) ? expf(alfa[ie]) : 0.0f;
    const float inv = 1.0f / (e0 + e1);
    const float w0 = e0 * inv;
    const float w1v = e1 * inv;

    const float* __restrict__ sp1 = states + (size_t)i1 * D_STATE;
    const float* __restrict__ sp2 = states + (size_t)i2 * D_STATE;
    const float* __restrict__ em1 = embeds + (size_t)i1 * D_EMB;
    const float* __restrict__ em2 = embeds + (size_t)ie * D_EMB;
    const float* __restrict__ wt = wtab + (size_t)(wdt + 1) * D_DIST;
    float* __restrict__ grow = gi + (size_t)s * GI_DIM;
    unsigned short* __restrict__ hrow = W16 ? (gi16 + (size_t)s * KP16) : (unsigned short*)0;

    // ---- phase 1: gather 5 float4 windows per lane (loads batched) ----
    float v[5][4];
#pragma unroll
    for (int i = 0; i < 5; ++i) {
        const int j = (i * 64 + lane) * 4;
        if (j + 4 <= 400) {
            float4 q = *(const float4*)(sp1 + j);
            v[i][0] = q.x; v[i][1] = q.y; v[i][2] = q.z; v[i][3] = q.w;
        } else if (j >= 400 && j + 4 <= 800) {
            float4 q = *(const float4*)(sp2 + (j - 400));
            v[i][0] = q.x; v[i][1] = q.y; v[i][2] = q.z; v[i][3] = q.w;
        } else if (j >= 800 && j + 4 <= 1148) {
            const int jj = j - 800;
            float2 a0 = *(const float2*)(em1 + jj);
            float2 a1 = *(const float2*)(em1 + jj + 2);
            float2 b0 = *(const float2*)(em2 + jj);
            float2 b1 = *(const float2*)(em2 + jj + 2);
            v[i][0] = w0 * a0.x + w1v * b0.x;
            v[i][1] = w0 * a0.y + w1v * b0.y;
            v[i][2] = w0 * a1.x + w1v * b1.x;
            v[i][3] = w0 * a1.y + w1v * b1.y;
        } else if (j < KP16) {
#pragma unroll
            for (int q = 0; q < 4; ++q) {
                const int jq = j + q;
                float val;
                if (jq < 400) val = sp1[jq];
                else if (jq < 800) val = sp2[jq - 400];
                else if (jq < 1150) val = w0 * em1[jq - 800] + w1v * em2[jq - 800];
                else if (jq < GI_DIM) val = wt[jq - 1150];
                else val = 0.f;
                v[i][q] = val;
            }
        }
    }

    // ---- phase 2: stores batched ----
#pragma unroll
    for (int i = 0; i < 5; ++i) {
        const int j = (i * 64 + lane) * 4;
        if (j >= KP16) continue;
        if (W16) {
            uint2 p;
            p.x = (unsigned int)f2bf(v[i][0]) | ((unsigned int)f2bf(v[i][1]) << 16);
            p.y = (unsigned int)f2bf(v[i][2]) | ((unsigned int)f2bf(v[i][3]) << 16);
            *(uint2*)(hrow + j) = p;
        }
        if (j + 2 <= GI_DIM) {
            f32x2 p01; p01.x = v[i][0]; p01.y = v[i][1];
            __builtin_nontemporal_store(p01, (f32x2*)(grow + j));
        }
        if (j + 4 <= GI_DIM) {
            f32x2 p23; p23.x = v[i][2]; p23.y = v[i][3];
            __builtin_nontemporal_store(p23, (f32x2*)(grow + j + 2));
        }
    }
}

// ---------------------------------------------------------------------------
// Mention GEMM v3: A double-buffered in LDS (single barrier per tile),
// B fragments read straight from L2-resident w1t (layer-2-proven pattern).
// A16 [N_S][1216] bf16 shadow.
// ---------------------------------------------------------------------------
__global__ __launch_bounds__(256) void mention_gemm3(
    const unsigned short* __restrict__ A16,
    const unsigned short* __restrict__ w1t, const float* __restrict__ b1,
    const unsigned short* __restrict__ w2t, const float* __restrict__ b2,
    const unsigned short* __restrict__ w3, const float* __restrict__ b3,
    float* __restrict__ out)
{
    __shared__ __align__(16) char smem[43008];   // sA[2] @ 0/16384; h1 reuses all

    const int tid = threadIdx.x;
    const int w = tid >> 6;
    const int l = tid & 63;
    const int l15 = l & 15;
    const int lg = l >> 4;
    const int row0 = blockIdx.x * 128;

    f32x4 acc[2][10];
#pragma unroll
    for (int rf = 0; rf < 2; ++rf)
#pragma unroll
        for (int nf = 0; nf < 10; ++nf) acc[rf][nf] = (f32x4){0.f, 0.f, 0.f, 0.f};

    const int arow_base = w * 32 + l15;
    const int asw = (arow_base & 7) << 4;

    // ---- prologue: load + stage tile 0 ----
    s16x8 va[4];
#pragma unroll
    for (int i = 0; i < 4; ++i) {
        int j = i * 256 + tid; int row = j >> 3, sub = j & 7;
        va[i] = *(const s16x8*)(A16 + (size_t)(row0 + row) * KP16 + sub * 8);
    }
#pragma unroll
    for (int i = 0; i < 4; ++i) {
        int j = i * 256 + tid; int row = j >> 3, sub = j & 7;
        *(s16x8*)(smem + row * 128 + ((sub * 16) ^ ((row & 7) << 4))) = va[i];
    }
    __syncthreads();

    for (int t = 0; t < 19; ++t) {
        const char* sA = smem + (t & 1) * 16384;

        // issue A loads for t+1 (land during MFMA phase)
        if (t + 1 < 19) {
            const int k0 = (t + 1) * 64;
#pragma unroll
            for (int i = 0; i < 4; ++i) {
                int j = i * 256 + tid; int row = j >> 3, sub = j & 7;
                va[i] = *(const s16x8*)(A16 + (size_t)(row0 + row) * KP16 + k0 + sub * 8);
            }
        }

        // MFMA: A from LDS[cur], B straight from L2-resident w1t
        const unsigned short* __restrict__ bk = w1t + t * 64;
#pragma unroll
        for (int kc = 0; kc < 2; ++kc) {
            const int inrowA = kc * 64 + lg * 16;
            s16x8 a0 = *(const s16x8*)(sA + arow_base * 128 + (inrowA ^ asw));
            s16x8 a1 = *(const s16x8*)(sA + arow_base * 128 + 2048 + (inrowA ^ asw));
            const unsigned short* __restrict__ bkk = bk + kc * 32 + lg * 8;
#pragma unroll
            for (int nf = 0; nf < 10; ++nf) {
                const int n = nf * 16 + l15;
                s16x8 b = *(const s16x8*)(bkk + (size_t)n * KP16);
                acc[0][nf] = __builtin_amdgcn_mfma_f32_16x16x32_bf16(a0, b, acc[0][nf], 0, 0, 0);
                acc[1][nf] = __builtin_amdgcn_mfma_f32_16x16x32_bf16(a1, b, acc[1][nf], 0, 0, 0);
            }
        }

        // stage t+1 into the other buffer; one barrier per tile
        if (t + 1 < 19) {
            char* sAn = smem + ((t + 1) & 1) * 16384;
#pragma unroll
            for (int i = 0; i < 4; ++i) {
                int j = i * 256 + tid; int row = j >> 3, sub = j & 7;
                *(s16x8*)(sAn + row * 128 + ((sub * 16) ^ ((row & 7) << 4))) = va[i];
            }
        }
        __syncthreads();
    }

    // ---- h1 = relu(acc + b1) -> LDS bf16 [128][336B] (loop barrier synced) ----
    {
        float b1c[10];
#pragma unroll
        for (int nf = 0; nf < 10; ++nf) {
            int col = nf * 16 + l15;
            b1c[nf] = (col < HDIM) ? b1[col] : 0.f;
        }
#pragma unroll
        for (int rf = 0; rf < 2; ++rf)
#pragma unroll
            for (int nf = 0; nf < 10; ++nf)
#pragma unroll
                for (int r = 0; r < 4; ++r) {
                    int row = w * 32 + rf * 16 + lg * 4 + r;
                    int col = nf * 16 + l15;
                    float h = fmaxf(acc[rf][nf][r] + b1c[nf], 0.f);
                    *(unsigned short*)(smem + row * 336 + col * 2) = f2bf(h);
                }
    }
    __syncthreads();

    // ---- layer 2 ----
    f32x4 acc2[2][10];
#pragma unroll
    for (int rf = 0; rf < 2; ++rf)
#pragma unroll
        for (int nf = 0; nf < 10; ++nf) acc2[rf][nf] = (f32x4){0.f, 0.f, 0.f, 0.f};

#pragma unroll
    for (int kc = 0; kc < 5; ++kc) {
        s16x8 a0 = *(const s16x8*)(smem + (w * 32 + l15) * 336 + kc * 64 + lg * 16);
        s16x8 a1 = *(const s16x8*)(smem + (w * 32 + 16 + l15) * 336 + kc * 64 + lg * 16);
#pragma unroll
        for (int nf = 0; nf < 10; ++nf) {
            const int n = nf * 16 + l15;
            s16x8 b = *(const s16x8*)(w2t + n * 160 + kc * 32 + lg * 8);
            acc2[0][nf] = __builtin_amdgcn_mfma_f32_16x16x32_bf16(a0, b, acc2[0][nf], 0, 0, 0);
            acc2[1][nf] = __builtin_amdgcn_mfma_f32_16x16x32_bf16(a1, b, acc2[1][nf], 0, 0, 0);
        }
    }

    // ---- layer 3 ----
    {
        float b2c[10], w3c[10];
#pragma unroll
        for (int nf = 0; nf < 10; ++nf) {
            int col = nf * 16 + l15;
            b2c[nf] = (col < HDIM) ? b2[col] : 0.f;
            w3c[nf] = bf2f(w3[col]);
        }
#pragma unroll
        for (int rf = 0; rf < 2; ++rf)
#pragma unroll
            for (int r = 0; r < 4; ++r) {
                float ps = 0.f;
#pragma unroll
                for (int nf = 0; nf < 10; ++nf)
                    ps += fmaxf(acc2[rf][nf][r] + b2c[nf], 0.f) * w3c[nf];
                ps += __shfl_xor(ps, 1);
                ps += __shfl_xor(ps, 2);
                ps += __shfl_xor(ps, 4);
                ps += __shfl_xor(ps, 8);
                if (l15 == 0)
                    out[row0 + w * 32 + rf * 16 + lg * 4 + r] = ps + b3[0];
            }
    }
}

// ---------------------------------------------------------------------------
// Fallback / alfa MLP (proven round-2 kernel): A [M][K] f32 -> out [M]
// ---------------------------------------------------------------------------
template <int K, int NT>
__global__ __launch_bounds__(256) void mlp_mfma(
    const float* __restrict__ A,
    const unsigned short* __restrict__ w1t, const float* __restrict__ b1,
    const unsigned short* __restrict__ w2t, const float* __restrict__ b2,
    const unsigned short* __restrict__ w3, const float* __restrict__ b3,
    float* __restrict__ out)
{
    constexpr int KP = NT * 64;
    __shared__ __align__(16) char smem[43008];
    const int SB_OFF = 16384;

    const int tid = threadIdx.x;
    const int w = tid >> 6;
    const int l = tid & 63;
    const int l15 = l & 15;
    const int lg = l >> 4;
    const int row0 = blockIdx.x * 128;

    const int arow = tid >> 1;
    const int acb = (tid & 1) * 32;

    f32x4 acc[2][10];
#pragma unroll
    for (int rf = 0; rf < 2; ++rf)
#pragma unroll
        for (int nf = 0; nf < 10; ++nf) acc[rf][nf] = (f32x4){0.f, 0.f, 0.f, 0.f};

    const int arow_base = w * 32 + l15;
    const int asw = (arow_base & 7) << 4;

    for (int t = 0; t < NT; ++t) {
        const int k0 = t * 64;
        __syncthreads();

        unsigned short tmp[32];
        if (k0 + 64 <= K) {
            const float* src = A + (size_t)(row0 + arow) * K + k0 + acb;
#pragma unroll
            for (int i = 0; i < 16; ++i) {
                float2 v = ((const float2*)src)[i];
                tmp[2 * i] = f2bf(v.x);
                tmp[2 * i + 1] = f2bf(v.y);
            }
        } else {
            const float* arp = A + (size_t)(row0 + arow) * K;
#pragma unroll
            for (int i = 0; i < 32; ++i) {
                int col = k0 + acb + i;
                tmp[i] = (col < K) ? f2bf(arp[col]) : (unsigned short)0;
            }
        }
        {
            const int sw = (arow & 7) << 4;
#pragma unroll
            for (int i = 0; i < 4; ++i) {
                s16x8 pv;
#pragma unroll
                for (int j = 0; j < 8; ++j) pv[j] = (short)tmp[i * 8 + j];
                int inrow = acb * 2 + i * 16;
                *(s16x8*)(smem + arow * 128 + (inrow ^ sw)) = pv;
            }
        }

#pragma unroll
        for (int i = 0; i < 5; ++i) {
            int idx = i * 256 + tid;
            int n = idx >> 3, s2 = idx & 7;
            s16x8 v = *(const s16x8*)(w1t + (size_t)n * KP + k0 + s2 * 8);
            int inrow = s2 * 16;
            *(s16x8*)(smem + SB_OFF + n * 128 + (inrow ^ ((n & 7) << 4))) = v;
        }

        __syncthreads();

#pragma unroll
        for (int kc = 0; kc < 2; ++kc) {
            const int inrowA = kc * 64 + lg * 16;
            s16x8 a0 = *(const s16x8*)(smem + arow_base * 128 + (inrowA ^ asw));
            s16x8 a1 = *(const s16x8*)(smem + arow_base * 128 + 2048 + (inrowA ^ asw));
#pragma unroll
            for (int nf = 0; nf < 10; ++nf) {
                const int n = nf * 16 + l15;
                s16x8 b = *(const s16x8*)(smem + SB_OFF + n * 128 + (inrowA ^ ((n & 7) << 4)));
                acc[0][nf] = __builtin_amdgcn_mfma_f32_16x16x32_bf16(a0, b, acc[0][nf], 0, 0, 0);
                acc[1][nf] = __builtin_amdgcn_mfma_f32_16x16x32_bf16(a1, b, acc[1][nf], 0, 0, 0);
            }
        }
    }

    __syncthreads();

    {
        float b1c[10];
#pragma unroll
        for (int nf = 0; nf < 10; ++nf) {
            int col = nf * 16 + l15;
            b1c[nf] = (col < HDIM) ? b1[col] : 0.f;
        }
#pragma unroll
        for (int rf = 0; rf < 2; ++rf)
#pragma unroll
            for (int nf = 0; nf < 10; ++nf)
#pragma unroll
                for (int r = 0; r < 4; ++r) {
                    int row = w * 32 + rf * 16 + lg * 4 + r;
                    int col = nf * 16 + l15;
                    float h = fmaxf(acc[rf][nf][r] + b1c[nf], 0.f);
                    *(unsigned short*)(smem + row * 336 + col * 2) = f2bf(h);
                }
    }
    __syncthreads();

    f32x4 acc2[2][10];
#pragma unroll
    for (int rf = 0; rf < 2; ++rf)
#pragma unroll
        for (int nf = 0; nf < 10; ++nf) acc2[rf][nf] = (f32x4){0.f, 0.f, 0.f, 0.f};

#pragma unroll
    for (int kc = 0; kc < 5; ++kc) {
        s16x8 a0 = *(const s16x8*)(smem + (w * 32 + l15) * 336 + kc * 64 + lg * 16);
        s16x8 a1 = *(const s16x8*)(smem + (w * 32 + 16 + l15) * 336 + kc * 64 + lg * 16);
#pragma unroll
        for (int nf = 0; nf < 10; ++nf) {
            const int n = nf * 16 + l15;
            s16x8 b = *(const s16x8*)(w2t + n * 160 + kc * 32 + lg * 8);
            acc2[0][nf] = __builtin_amdgcn_mfma_f32_16x16x32_bf16(a0, b, acc2[0][nf], 0, 0, 0);
            acc2[1][nf] = __builtin_amdgcn_mfma_f32_16x16x32_bf16(a1, b, acc2[1][nf], 0, 0, 0);
        }
    }

    {
        float b2c[10], w3c[10];
#pragma unroll
        for (int nf = 0; nf < 10; ++nf) {
            int col = nf * 16 + l15;
            b2c[nf] = (col < HDIM) ? b2[col] : 0.f;
            w3c[nf] = bf2f(w3[col]);
        }
#pragma unroll
        for (int rf = 0; rf < 2; ++rf)
#pragma unroll
            for (int r = 0; r < 4; ++r) {
                float ps = 0.f;
#pragma unroll
                for (int nf = 0; nf < 10; ++nf)
                    ps += fmaxf(acc2[rf][nf][r] + b2c[nf], 0.f) * w3c[nf];
                ps += __shfl_xor(ps, 1);
                ps += __shfl_xor(ps, 2);
                ps += __shfl_xor(ps, 4);
                ps += __shfl_xor(ps, 8);
                if (l15 == 0)
                    out[row0 + w * 32 + rf * 16 + lg * 4 + r] = ps + b3[0];
            }
    }
}

extern "C" void kernel_launch(void* const* d_in, const int* in_sizes, int n_in,
                              void* d_out, int out_size, void* d_ws, size_t ws_size,
                              hipStream_t stream)
{
    const float* states = (const float*)d_in[0];
    const float* embeds = (const float*)d_in[1];
    const int*   starts = (const int*)d_in[2];
    const int*   widths = (const int*)d_in[3];
    const float* aW1 = (const float*)d_in[4];
    const float* ab1 = (const float*)d_in[5];
    const float* aW2 = (const float*)d_in[6];
    const float* ab2 = (const float*)d_in[7];
    const float* aW3 = (const float*)d_in[8];
    const float* ab3 = (const float*)d_in[9];
    const float* wtab = (const float*)d_in[10];
    const float* sW1 = (const float*)d_in[11];
    const float* sb1 = (const float*)d_in[12];
    const float* sW2 = (const float*)d_in[13];
    const float* sb2 = (const float*)d_in[14];
    const float* sW3 = (const float*)d_in[15];
    const float* sb3 = (const float*)d_in[16];

    float* gi = (float*)d_out;
    float* scores = gi + (size_t)N_S * GI_DIM;

    char* ws = (char*)d_ws;
    float* alfa = (float*)ws;                                   // 320000 B
    unsigned short* w1t_m = (unsigned short*)(ws + 320512);     // 389120
    unsigned short* w2t_m = (unsigned short*)(ws + 709632);     // 51200
    unsigned short* w3_m  = (unsigned short*)(ws + 760832);     // 320
    unsigned short* w1t_a = (unsigned short*)(ws + 761344);     // 143360
    unsigned short* w2t_a = (unsigned short*)(ws + 904704);     // 51200
    unsigned short* w3_a  = (unsigned short*)(ws + 955904);     // 320
    const size_t GI16_OFF = 956416;
    const size_t GI16_BYTES = (size_t)N_S * KP16 * 2;           // 389.12 MB
    unsigned short* gi16 = (unsigned short*)(ws + GI16_OFF);
    const bool have_ws = (ws_size >= GI16_OFF + GI16_BYTES);

    // 0) convert/transpose/pad weights to bf16
    convert_kernel<<<1242, 256, 0, stream>>>(sW1, sW2, sW3, aW1, aW2, aW3,
                                             w1t_m, w2t_m, w3_m, w1t_a, w2t_a, w3_a);

    // 1) alfa = attention-MLP(states)
    mlp_mfma<D_STATE, 7><<<N_T / 128, 256, 0, stream>>>(
        states, w1t_a, ab1, w2t_a, ab2, w3_a, ab3, alfa);

    if (have_ws) {
        // 2) g_i build: f32 output + bf16 shadow
        gi_build<1><<<N_S / 4, 256, 0, stream>>>(
            states, embeds, starts, widths, alfa, wtab, gi, gi16);
        // 3) GEMM v3: A-dbuf single-barrier, B direct from L2
        mention_gemm3<<<N_S / 128, 256, 0, stream>>>(
            gi16, w1t_m, sb1, w2t_m, sb2, w3_m, sb3, scores);
    } else {
        // fallback: f32 g_i only, proven round-2 GEMM from f32
        gi_build<0><<<N_S / 4, 256, 0, stream>>>(
            states, embeds, starts, widths, alfa, wtab, gi, (unsigned short*)0);
        mlp_mfma<GI_DIM, 19><<<N_S / 128, 256, 0, stream>>>(
            gi, w1t_m, sb1, w2t_m, sb2, w3_m, sb3, scores);
    }
}

// Round 11
// 506.582 us; speedup vs baseline: 1.4978x; 1.4978x over previous
//
#include <hip/hip_runtime.h>
#include <math.h>

#define N_T 80000
#define N_S 160000
#define D_STATE 400
#define D_EMB 350
#define D_DIST 20
#define HDIM 150
#define GI_DIM 1170
#define KP16 1216   // padded K for bf16 shadow / weights

typedef __attribute__((ext_vector_type(8))) short s16x8;
typedef __attribute__((ext_vector_type(4))) float f32x4;
typedef __attribute__((ext_vector_type(2))) float f32x2;   // clang vector: OK for nontemporal builtins

__device__ __forceinline__ unsigned short f2bf(float f) {
    union { float f; unsigned int u; } c; c.f = f;
    unsigned int u = c.u;
    unsigned int r = (u + 0x7fffu + ((u >> 16) & 1u)) >> 16;  // RNE
    return (unsigned short)r;
}
__device__ __forceinline__ float bf2f(unsigned short h) {
    union { unsigned int u; float f; } c; c.u = ((unsigned int)h) << 16;
    return c.f;
}

// ---------------------------------------------------------------------------
// Weight conversion: f32 [K][150] -> bf16 transposed+padded [160][KP]
// ---------------------------------------------------------------------------
__global__ __launch_bounds__(256) void convert_kernel(
    const float* __restrict__ sW1, const float* __restrict__ sW2, const float* __restrict__ sW3,
    const float* __restrict__ aW1, const float* __restrict__ aW2, const float* __restrict__ aW3,
    unsigned short* __restrict__ w1t_m, unsigned short* __restrict__ w2t_m, unsigned short* __restrict__ w3_m,
    unsigned short* __restrict__ w1t_a, unsigned short* __restrict__ w2t_a, unsigned short* __restrict__ w3_a)
{
    int gid = blockIdx.x * 256 + threadIdx.x;
    const int S1 = 160 * 1216, S2 = 160 * 160, S3 = 160, S4 = 160 * 448, S5 = 160 * 160, S6 = 160;
    if (gid < S1) {
        int n = gid / 1216, k = gid % 1216;
        float v = (k < GI_DIM && n < HDIM) ? sW1[k * HDIM + n] : 0.f;
        w1t_m[gid] = f2bf(v); return;
    } gid -= S1;
    if (gid < S2) {
        int n = gid / 160, k = gid % 160;
        float v = (k < HDIM && n < HDIM) ? sW2[k * HDIM + n] : 0.f;
        w2t_m[gid] = f2bf(v); return;
    } gid -= S2;
    if (gid < S3) { w3_m[gid] = (gid < HDIM) ? f2bf(sW3[gid]) : (unsigned short)0; return; } gid -= S3;
    if (gid < S4) {
        int n = gid / 448, k = gid % 448;
        float v = (k < D_STATE && n < HDIM) ? aW1[k * HDIM + n] : 0.f;
        w1t_a[gid] = f2bf(v); return;
    } gid -= S4;
    if (gid < S5) {
        int n = gid / 160, k = gid % 160;
        float v = (k < HDIM && n < HDIM) ? aW2[k * HDIM + n] : 0.f;
        w2t_a[gid] = f2bf(v); return;
    } gid -= S5;
    if (gid < S6) { w3_a[gid] = (gid < HDIM) ? f2bf(aW3[gid]) : (unsigned short)0; }
}

// ---------------------------------------------------------------------------
// g_i build v2: one wave per span, fixed 5-window float4 layout per lane.
// Phase 1: batch ALL gather loads into registers (deep MLP).
// Phase 2: batch all stores (nontemporal f32 gi + packed bf16 shadow).
// ---------------------------------------------------------------------------
template <int W16>
__global__ __launch_bounds__(256) void gi_build(
    const float* __restrict__ states, const float* __restrict__ embeds,
    const int* __restrict__ starts, const int* __restrict__ widths,
    const float* __restrict__ alfa, const float* __restrict__ wtab,
    float* __restrict__ gi, unsigned short* __restrict__ gi16)
{
    const int wave = threadIdx.x >> 6;
    const int lane = threadIdx.x & 63;
    const int s = blockIdx.x * 4 + wave;

    const int i1 = starts[s];
    const int wdt = widths[s];
    int i2 = i1 + wdt; if (i2 > N_T - 1) i2 = N_T - 1;
    int ie = i1 + 1;  if (ie > N_T - 1) ie = N_T - 1;

    const float e0 = expf(alfa[i1]);
    const float e1 = (wdt > 0) ? expf(alfa[ie]) : 0.0f;
    const float inv = 1.0f / (e0 + e1);
    const float w0 = e0 * inv;
    const float w1v = e1 * inv;

    const float* __restrict__ sp1 = states + (size_t)i1 * D_STATE;
    const float* __restrict__ sp2 = states + (size_t)i2 * D_STATE;
    const float* __restrict__ em1 = embeds + (size_t)i1 * D_EMB;
    const float* __restrict__ em2 = embeds + (size_t)ie * D_EMB;
    const float* __restrict__ wt = wtab + (size_t)(wdt + 1) * D_DIST;
    float* __restrict__ grow = gi + (size_t)s * GI_DIM;
    unsigned short* __restrict__ hrow = W16 ? (gi16 + (size_t)s * KP16) : (unsigned short*)0;

    // ---- phase 1: gather 5 float4 windows per lane (loads batched) ----
    float v[5][4];
#pragma unroll
    for (int i = 0; i < 5; ++i) {
        const int j = (i * 64 + lane) * 4;
        if (j + 4 <= 400) {
            // states[i1] segment; states rows are 16B-aligned (400*4B)
            float4 q = *(const float4*)(sp1 + j);
            v[i][0] = q.x; v[i][1] = q.y; v[i][2] = q.z; v[i][3] = q.w;
        } else if (j >= 400 && j + 4 <= 800) {
            float4 q = *(const float4*)(sp2 + (j - 400));
            v[i][0] = q.x; v[i][1] = q.y; v[i][2] = q.z; v[i][3] = q.w;
        } else if (j >= 800 && j + 4 <= 1148) {
            // attn segment; embeds rows only 8B-aligned (350*4B) -> float2 loads
            const int jj = j - 800;
            float2 a0 = *(const float2*)(em1 + jj);
            float2 a1 = *(const float2*)(em1 + jj + 2);
            float2 b0 = *(const float2*)(em2 + jj);
            float2 b1 = *(const float2*)(em2 + jj + 2);
            v[i][0] = w0 * a0.x + w1v * b0.x;
            v[i][1] = w0 * a0.y + w1v * b0.y;
            v[i][2] = w0 * a1.x + w1v * b1.x;
            v[i][3] = w0 * a1.y + w1v * b1.y;
        } else if (j < KP16) {
            // boundary / width / pad windows (scalar fallback, few lanes)
#pragma unroll
            for (int q = 0; q < 4; ++q) {
                const int jq = j + q;
                float val;
                if (jq < 400) val = sp1[jq];
                else if (jq < 800) val = sp2[jq - 400];
                else if (jq < 1150) val = w0 * em1[jq - 800] + w1v * em2[jq - 800];
                else if (jq < GI_DIM) val = wt[jq - 1150];
                else val = 0.f;
                v[i][q] = val;
            }
        }
    }

    // ---- phase 2: stores batched ----
#pragma unroll
    for (int i = 0; i < 5; ++i) {
        const int j = (i * 64 + lane) * 4;
        if (j >= KP16) continue;
        if (W16) {
            // packed bf16 shadow: 8B store, rows 16B-aligned (1216*2B)
            uint2 p;
            p.x = (unsigned int)f2bf(v[i][0]) | ((unsigned int)f2bf(v[i][1]) << 16);
            p.y = (unsigned int)f2bf(v[i][2]) | ((unsigned int)f2bf(v[i][3]) << 16);
            *(uint2*)(hrow + j) = p;
        }
        // f32 gi: rows only 8B-aligned (1170*4B) -> f32x2 nontemporal stores
        if (j + 2 <= GI_DIM) {
            f32x2 p01; p01.x = v[i][0]; p01.y = v[i][1];
            __builtin_nontemporal_store(p01, (f32x2*)(grow + j));
        }
        if (j + 4 <= GI_DIM) {
            f32x2 p23; p23.x = v[i][2]; p23.y = v[i][3];
            __builtin_nontemporal_store(p23, (f32x2*)(grow + j + 2));
        }
    }
}

// ---------------------------------------------------------------------------
// Clean bf16 GEMM + fused MLP layers 2/3: A16 [N_S][1216] bf16, branch-free
// batched staging with next-tile register prefetch (T14).
// ---------------------------------------------------------------------------
__global__ __launch_bounds__(256) void mention_gemm(
    const unsigned short* __restrict__ A16,
    const unsigned short* __restrict__ w1t, const float* __restrict__ b1,
    const unsigned short* __restrict__ w2t, const float* __restrict__ b2,
    const unsigned short* __restrict__ w3, const float* __restrict__ b3,
    float* __restrict__ out)
{
    __shared__ __align__(16) char smem[43008];
    const int SB_OFF = 16384;

    const int tid = threadIdx.x;
    const int w = tid >> 6;
    const int l = tid & 63;
    const int l15 = l & 15;
    const int lg = l >> 4;
    const int row0 = blockIdx.x * 128;

    f32x4 acc[2][10];
#pragma unroll
    for (int rf = 0; rf < 2; ++rf)
#pragma unroll
        for (int nf = 0; nf < 10; ++nf) acc[rf][nf] = (f32x4){0.f, 0.f, 0.f, 0.f};

    const int arow_base = w * 32 + l15;
    const int asw = (arow_base & 7) << 4;

    // batched staging registers (issue all loads back-to-back)
    s16x8 va[4], vb[5];
    {
        const int k0 = 0;
#pragma unroll
        for (int i = 0; i < 4; ++i) {
            int j = i * 256 + tid; int row = j >> 3, sub = j & 7;
            va[i] = *(const s16x8*)(A16 + (size_t)(row0 + row) * KP16 + k0 + sub * 8);
        }
#pragma unroll
        for (int i = 0; i < 5; ++i) {
            int idx = i * 256 + tid; int n = idx >> 3, s2 = idx & 7;
            vb[i] = *(const s16x8*)(w1t + (size_t)n * KP16 + k0 + s2 * 8);
        }
    }

    for (int t = 0; t < 19; ++t) {
        __syncthreads();   // all waves done reading previous LDS tile

        // ds_write staged registers (swizzled)
#pragma unroll
        for (int i = 0; i < 4; ++i) {
            int j = i * 256 + tid; int row = j >> 3, sub = j & 7;
            *(s16x8*)(smem + row * 128 + ((sub * 16) ^ ((row & 7) << 4))) = va[i];
        }
#pragma unroll
        for (int i = 0; i < 5; ++i) {
            int idx = i * 256 + tid; int n = idx >> 3, s2 = idx & 7;
            *(s16x8*)(smem + SB_OFF + n * 128 + ((s2 * 16) ^ ((n & 7) << 4))) = vb[i];
        }
        __syncthreads();

        // prefetch next tile (lands during MFMA phase)
        if (t + 1 < 19) {
            const int k0 = (t + 1) * 64;
#pragma unroll
            for (int i = 0; i < 4; ++i) {
                int j = i * 256 + tid; int row = j >> 3, sub = j & 7;
                va[i] = *(const s16x8*)(A16 + (size_t)(row0 + row) * KP16 + k0 + sub * 8);
            }
#pragma unroll
            for (int i = 0; i < 5; ++i) {
                int idx = i * 256 + tid; int n = idx >> 3, s2 = idx & 7;
                vb[i] = *(const s16x8*)(w1t + (size_t)n * KP16 + k0 + s2 * 8);
            }
        }

        // MFMA phase
#pragma unroll
        for (int kc = 0; kc < 2; ++kc) {
            const int inrowA = kc * 64 + lg * 16;
            s16x8 a0 = *(const s16x8*)(smem + arow_base * 128 + (inrowA ^ asw));
            s16x8 a1 = *(const s16x8*)(smem + arow_base * 128 + 2048 + (inrowA ^ asw));
#pragma unroll
            for (int nf = 0; nf < 10; ++nf) {
                const int n = nf * 16 + l15;
                s16x8 b = *(const s16x8*)(smem + SB_OFF + n * 128 + (inrowA ^ ((n & 7) << 4)));
                acc[0][nf] = __builtin_amdgcn_mfma_f32_16x16x32_bf16(a0, b, acc[0][nf], 0, 0, 0);
                acc[1][nf] = __builtin_amdgcn_mfma_f32_16x16x32_bf16(a1, b, acc[1][nf], 0, 0, 0);
            }
        }
    }

    __syncthreads();  // done with sA/sB, reuse as h1 buffer

    // ---- h1 = relu(acc + b1) -> LDS bf16 [128][336B] ----
    {
        float b1c[10];
#pragma unroll
        for (int nf = 0; nf < 10; ++nf) {
            int col = nf * 16 + l15;
            b1c[nf] = (col < HDIM) ? b1[col] : 0.f;
        }
#pragma unroll
        for (int rf = 0; rf < 2; ++rf)
#pragma unroll
            for (int nf = 0; nf < 10; ++nf)
#pragma unroll
                for (int r = 0; r < 4; ++r) {
                    int row = w * 32 + rf * 16 + lg * 4 + r;
                    int col = nf * 16 + l15;
                    float h = fmaxf(acc[rf][nf][r] + b1c[nf], 0.f);
                    *(unsigned short*)(smem + row * 336 + col * 2) = f2bf(h);
                }
    }
    __syncthreads();

    // ---- layer 2 ----
    f32x4 acc2[2][10];
#pragma unroll
    for (int rf = 0; rf < 2; ++rf)
#pragma unroll
        for (int nf = 0; nf < 10; ++nf) acc2[rf][nf] = (f32x4){0.f, 0.f, 0.f, 0.f};

#pragma unroll
    for (int kc = 0; kc < 5; ++kc) {
        s16x8 a0 = *(const s16x8*)(smem + (w * 32 + l15) * 336 + kc * 64 + lg * 16);
        s16x8 a1 = *(const s16x8*)(smem + (w * 32 + 16 + l15) * 336 + kc * 64 + lg * 16);
#pragma unroll
        for (int nf = 0; nf < 10; ++nf) {
            const int n = nf * 16 + l15;
            s16x8 b = *(const s16x8*)(w2t + n * 160 + kc * 32 + lg * 8);
            acc2[0][nf] = __builtin_amdgcn_mfma_f32_16x16x32_bf16(a0, b, acc2[0][nf], 0, 0, 0);
            acc2[1][nf] = __builtin_amdgcn_mfma_f32_16x16x32_bf16(a1, b, acc2[1][nf], 0, 0, 0);
        }
    }

    // ---- layer 3 ----
    {
        float b2c[10], w3c[10];
#pragma unroll
        for (int nf = 0; nf < 10; ++nf) {
            int col = nf * 16 + l15;
            b2c[nf] = (col < HDIM) ? b2[col] : 0.f;
            w3c[nf] = bf2f(w3[col]);
        }
#pragma unroll
        for (int rf = 0; rf < 2; ++rf)
#pragma unroll
            for (int r = 0; r < 4; ++r) {
                float ps = 0.f;
#pragma unroll
                for (int nf = 0; nf < 10; ++nf)
                    ps += fmaxf(acc2[rf][nf][r] + b2c[nf], 0.f) * w3c[nf];
                ps += __shfl_xor(ps, 1);
                ps += __shfl_xor(ps, 2);
                ps += __shfl_xor(ps, 4);
                ps += __shfl_xor(ps, 8);
                if (l15 == 0)
                    out[row0 + w * 32 + rf * 16 + lg * 4 + r] = ps + b3[0];
            }
    }
}

// ---------------------------------------------------------------------------
// Fallback / alfa MLP (proven round-2 kernel): A [M][K] f32 -> out [M]
// ---------------------------------------------------------------------------
template <int K, int NT>
__global__ __launch_bounds__(256) void mlp_mfma(
    const float* __restrict__ A,
    const unsigned short* __restrict__ w1t, const float* __restrict__ b1,
    const unsigned short* __restrict__ w2t, const float* __restrict__ b2,
    const unsigned short* __restrict__ w3, const float* __restrict__ b3,
    float* __restrict__ out)
{
    constexpr int KP = NT * 64;
    __shared__ __align__(16) char smem[43008];
    const int SB_OFF = 16384;

    const int tid = threadIdx.x;
    const int w = tid >> 6;
    const int l = tid & 63;
    const int l15 = l & 15;
    const int lg = l >> 4;
    const int row0 = blockIdx.x * 128;

    const int arow = tid >> 1;
    const int acb = (tid & 1) * 32;

    f32x4 acc[2][10];
#pragma unroll
    for (int rf = 0; rf < 2; ++rf)
#pragma unroll
        for (int nf = 0; nf < 10; ++nf) acc[rf][nf] = (f32x4){0.f, 0.f, 0.f, 0.f};

    const int arow_base = w * 32 + l15;
    const int asw = (arow_base & 7) << 4;

    for (int t = 0; t < NT; ++t) {
        const int k0 = t * 64;
        __syncthreads();

        unsigned short tmp[32];
        if (k0 + 64 <= K) {
            const float* src = A + (size_t)(row0 + arow) * K + k0 + acb;
#pragma unroll
            for (int i = 0; i < 16; ++i) {
                float2 v = ((const float2*)src)[i];
                tmp[2 * i] = f2bf(v.x);
                tmp[2 * i + 1] = f2bf(v.y);
            }
        } else {
            const float* arp = A + (size_t)(row0 + arow) * K;
#pragma unroll
            for (int i = 0; i < 32; ++i) {
                int col = k0 + acb + i;
                tmp[i] = (col < K) ? f2bf(arp[col]) : (unsigned short)0;
            }
        }
        {
            const int sw = (arow & 7) << 4;
#pragma unroll
            for (int i = 0; i < 4; ++i) {
                s16x8 pv;
#pragma unroll
                for (int j = 0; j < 8; ++j) pv[j] = (short)tmp[i * 8 + j];
                int inrow = acb * 2 + i * 16;
                *(s16x8*)(smem + arow * 128 + (inrow ^ sw)) = pv;
            }
        }

#pragma unroll
        for (int i = 0; i < 5; ++i) {
            int idx = i * 256 + tid;
            int n = idx >> 3, s2 = idx & 7;
            s16x8 v = *(const s16x8*)(w1t + (size_t)n * KP + k0 + s2 * 8);
            int inrow = s2 * 16;
            *(s16x8*)(smem + SB_OFF + n * 128 + (inrow ^ ((n & 7) << 4))) = v;
        }

        __syncthreads();

#pragma unroll
        for (int kc = 0; kc < 2; ++kc) {
            const int inrowA = kc * 64 + lg * 16;
            s16x8 a0 = *(const s16x8*)(smem + arow_base * 128 + (inrowA ^ asw));
            s16x8 a1 = *(const s16x8*)(smem + arow_base * 128 + 2048 + (inrowA ^ asw));
#pragma unroll
            for (int nf = 0; nf < 10; ++nf) {
                const int n = nf * 16 + l15;
                s16x8 b = *(const s16x8*)(smem + SB_OFF + n * 128 + (inrowA ^ ((n & 7) << 4)));
                acc[0][nf] = __builtin_amdgcn_mfma_f32_16x16x32_bf16(a0, b, acc[0][nf], 0, 0, 0);
                acc[1][nf] = __builtin_amdgcn_mfma_f32_16x16x32_bf16(a1, b, acc[1][nf], 0, 0, 0);
            }
        }
    }

    __syncthreads();

    {
        float b1c[10];
#pragma unroll
        for (int nf = 0; nf < 10; ++nf) {
            int col = nf * 16 + l15;
            b1c[nf] = (col < HDIM) ? b1[col] : 0.f;
        }
#pragma unroll
        for (int rf = 0; rf < 2; ++rf)
#pragma unroll
            for (int nf = 0; nf < 10; ++nf)
#pragma unroll
                for (int r = 0; r < 4; ++r) {
                    int row = w * 32 + rf * 16 + lg * 4 + r;
                    int col = nf * 16 + l15;
                    float h = fmaxf(acc[rf][nf][r] + b1c[nf], 0.f);
                    *(unsigned short*)(smem + row * 336 + col * 2) = f2bf(h);
                }
    }
    __syncthreads();

    f32x4 acc2[2][10];
#pragma unroll
    for (int rf = 0; rf < 2; ++rf)
#pragma unroll
        for (int nf = 0; nf < 10; ++nf) acc2[rf][nf] = (f32x4){0.f, 0.f, 0.f, 0.f};

#pragma unroll
    for (int kc = 0; kc < 5; ++kc) {
        s16x8 a0 = *(const s16x8*)(smem + (w * 32 + l15) * 336 + kc * 64 + lg * 16);
        s16x8 a1 = *(const s16x8*)(smem + (w * 32 + 16 + l15) * 336 + kc * 64 + lg * 16);
#pragma unroll
        for (int nf = 0; nf < 10; ++nf) {
            const int n = nf * 16 + l15;
            s16x8 b = *(const s16x8*)(w2t + n * 160 + kc * 32 + lg * 8);
            acc2[0][nf] = __builtin_amdgcn_mfma_f32_16x16x32_bf16(a0, b, acc2[0][nf], 0, 0, 0);
            acc2[1][nf] = __builtin_amdgcn_mfma_f32_16x16x32_bf16(a1, b, acc2[1][nf], 0, 0, 0);
        }
    }

    {
        float b2c[10], w3c[10];
#pragma unroll
        for (int nf = 0; nf < 10; ++nf) {
            int col = nf * 16 + l15;
            b2c[nf] = (col < HDIM) ? b2[col] : 0.f;
            w3c[nf] = bf2f(w3[col]);
        }
#pragma unroll
        for (int rf = 0; rf < 2; ++rf)
#pragma unroll
            for (int r = 0; r < 4; ++r) {
                float ps = 0.f;
#pragma unroll
                for (int nf = 0; nf < 10; ++nf)
                    ps += fmaxf(acc2[rf][nf][r] + b2c[nf], 0.f) * w3c[nf];
                ps += __shfl_xor(ps, 1);
                ps += __shfl_xor(ps, 2);
                ps += __shfl_xor(ps, 4);
                ps += __shfl_xor(ps, 8);
                if (l15 == 0)
                    out[row0 + w * 32 + rf * 16 + lg * 4 + r] = ps + b3[0];
            }
    }
}

extern "C" void kernel_launch(void* const* d_in, const int* in_sizes, int n_in,
                              void* d_out, int out_size, void* d_ws, size_t ws_size,
                              hipStream_t stream)
{
    const float* states = (const float*)d_in[0];
    const float* embeds = (const float*)d_in[1];
    const int*   starts = (const int*)d_in[2];
    const int*   widths = (const int*)d_in[3];
    const float* aW1 = (const float*)d_in[4];
    const float* ab1 = (const float*)d_in[5];
    const float* aW2 = (const float*)d_in[6];
    const float* ab2 = (const float*)d_in[7];
    const float* aW3 = (const float*)d_in[8];
    const float* ab3 = (const float*)d_in[9];
    const float* wtab = (const float*)d_in[10];
    const float* sW1 = (const float*)d_in[11];
    const float* sb1 = (const float*)d_in[12];
    const float* sW2 = (const float*)d_in[13];
    const float* sb2 = (const float*)d_in[14];
    const float* sW3 = (const float*)d_in[15];
    const float* sb3 = (const float*)d_in[16];

    float* gi = (float*)d_out;
    float* scores = gi + (size_t)N_S * GI_DIM;

    char* ws = (char*)d_ws;
    float* alfa = (float*)ws;                                   // 320000 B
    unsigned short* w1t_m = (unsigned short*)(ws + 320512);     // 389120
    unsigned short* w2t_m = (unsigned short*)(ws + 709632);     // 51200
    unsigned short* w3_m  = (unsigned short*)(ws + 760832);     // 320
    unsigned short* w1t_a = (unsigned short*)(ws + 761344);     // 143360
    unsigned short* w2t_a = (unsigned short*)(ws + 904704);     // 51200
    unsigned short* w3_a  = (unsigned short*)(ws + 955904);     // 320
    const size_t GI16_OFF = 956416;
    const size_t GI16_BYTES = (size_t)N_S * KP16 * 2;           // 389.12 MB
    unsigned short* gi16 = (unsigned short*)(ws + GI16_OFF);
    const bool have_ws = (ws_size >= GI16_OFF + GI16_BYTES);

    // 0) convert/transpose/pad weights to bf16
    convert_kernel<<<1242, 256, 0, stream>>>(sW1, sW2, sW3, aW1, aW2, aW3,
                                             w1t_m, w2t_m, w3_m, w1t_a, w2t_a, w3_a);

    // 1) alfa = attention-MLP(states)
    mlp_mfma<D_STATE, 7><<<N_T / 128, 256, 0, stream>>>(
        states, w1t_a, ab1, w2t_a, ab2, w3_a, ab3, alfa);

    if (have_ws) {
        // 2) g_i build: f32 output + bf16 shadow (batched loads, nt stores)
        gi_build<1><<<N_S / 4, 256, 0, stream>>>(
            states, embeds, starts, widths, alfa, wtab, gi, gi16);
        // 3) clean bf16 GEMM + MLP layers 2/3
        mention_gemm<<<N_S / 128, 256, 0, stream>>>(
            gi16, w1t_m, sb1, w2t_m, sb2, w3_m, sb3, scores);
    } else {
        // fallback: f32 g_i only, proven round-2 GEMM from f32
        gi_build<0><<<N_S / 4, 256, 0, stream>>>(
            states, embeds, starts, widths, alfa, wtab, gi, (unsigned short*)0);
        mlp_mfma<GI_DIM, 19><<<N_S / 128, 256, 0, stream>>>(
            gi, w1t_m, sb1, w2t_m, sb2, w3_m, sb3, scores);
    }
}